// Round 9
// baseline (288.378 us; speedup 1.0000x reference)
//
#include <hip/hip_runtime.h>
#include <math.h>

#define NLEV 24
#define CAPM 262144
#define TPW 2   // tiles (of 16 points) per wave in the MFMA MLP

typedef __attribute__((ext_vector_type(8))) short bf16x8;
typedef __attribute__((ext_vector_type(4))) float f32x4;
typedef __attribute__((ext_vector_type(2))) float f32x2;   // clang-native, OK for nontemporal builtins

// Intra-wave LDS ordering: DS ops from one wave execute in order; this wait
// makes write results visible to subsequent same-wave reads and stops the
// compiler reordering across it. No block barrier needed (per-wave LDS only).
#define LDS_SYNC() asm volatile("s_waitcnt lgkmcnt(0)" ::: "memory")

__device__ __forceinline__ unsigned short f2bf(float f) {   // RNE fp32->bf16
    unsigned u = __float_as_uint(f);
    u += 0x7FFFu + ((u >> 16) & 1u);
    return (unsigned short)(u >> 16);
}

__device__ __forceinline__ float gelu_exact(float v) {
    return 0.5f * v * (1.0f + erff(v * 0.70710678118654752f));
}

// ws layout: floats [0..23] 1/scale, [24..47] c2f window, [48] La;
// uint feat[24][N] (packed bf16 pair per level/point) from byte 1024.
__global__ void init_consts(const int* __restrict__ iter_p, float* __restrict__ ws) {
    __shared__ float wloc[NLEV];
    int l = threadIdx.x;
    if (l < NLEV) {
        double scale;
        if (l == 0) scale = 1.0;
        else if (l == NLEV - 1) scale = 0.0001;
        else scale = pow(10.0, -((double)(4 * l)) / 23.0);
        float scale_f = (float)scale;                 // reference casts geomspace to fp32
        ws[l] = (float)(1.0 / (double)scale_f);       // correctly-rounded fp32 reciprocal
        float t = (float)iter_p[0] / 10000.0f;
        t = fminf(fmaxf(t, 0.0f), 1.0f);
        float alpha = (0.3f + 0.7f * t) * 24.0f;
        float x = fminf(fmaxf(alpha - (float)l, 0.0f), 1.0f);
        float win = 0.5f * (1.0f - (float)cos(M_PI * (double)x));
        ws[NLEV + l] = win;
        wloc[l] = win;
    }
    __syncthreads();
    if (l == 0) {
        int cnt = 0;
        for (int i = 0; i < NLEV; i++) cnt += (wloc[i] > 0.0f) ? 1 : 0;
        ws[2 * NLEV] = (float)cnt;
    }
}

// Permutohedral lattice setup: verified arithmetic from rounds 1/3/4.
__device__ __forceinline__ void level_setup(
    float px, float py, float pz,
    const float* __restrict__ shifts, const float* __restrict__ cons, int l,
    float* __restrict__ wgt /*4*/, unsigned* __restrict__ hh /*4*/)
{
    const float SF0 = 2.3094010767585034f;  // 4/sqrt(3)
    const float SF1 = 1.3333333333333333f;  // 4/3
    const float SF2 = 0.9428090415820634f;  // 2*sqrt(2)/3

    float win = cons[NLEV + l];
    float inv = cons[l];
    float p0 = fmaf(px, inv, shifts[3 * l + 0]);
    float p1 = fmaf(py, inv, shifts[3 * l + 1]);
    float p2 = fmaf(pz, inv, shifts[3 * l + 2]);
    float c0 = p0 * SF0, c1 = p1 * SF1, c2 = p2 * SF2;
    float s1 = c1 + c2;
    float s0 = c0 + s1;
    float e0 = s0;
    float e1 = s1 - c0;
    float e2 = c2 - 2.0f * c1;
    float e3 = -3.0f * c2;
    float r0f = rintf(e0 * 0.25f) * 4.0f;
    float r1f = rintf(e1 * 0.25f) * 4.0f;
    float r2f = rintf(e2 * 0.25f) * 4.0f;
    float r3f = rintf(e3 * 0.25f) * 4.0f;
    int sum_ = (int)rintf((r0f + r1f + r2f + r3f) * 0.25f);
    float d0 = e0 - r0f, d1 = e1 - r1f, d2 = e2 - r2f, d3 = e3 - r3f;
    int k0 = (int)(d1 > d0) + (int)(d2 > d0) + (int)(d3 > d0) + sum_;
    int k1 = (int)(d0 > d1) + (int)(d2 > d1) + (int)(d3 > d1)
           + (int)(d0 == d1) + sum_;
    int k2 = (int)(d0 > d2) + (int)(d1 > d2) + (int)(d3 > d2)
           + (int)(d0 == d2) + (int)(d1 == d2) + sum_;
    int k3 = (int)(d0 > d3) + (int)(d1 > d3) + (int)(d2 > d3)
           + (int)(d0 == d3) + (int)(d1 == d3) + (int)(d2 == d3) + sum_;
    int a0 = (k0 < 0) ? 4 : ((k0 > 3) ? -4 : 0); k0 += a0; r0f += (float)a0;
    int a1 = (k1 < 0) ? 4 : ((k1 > 3) ? -4 : 0); k1 += a1; r1f += (float)a1;
    int a2 = (k2 < 0) ? 4 : ((k2 > 3) ? -4 : 0); k2 += a2; r2f += (float)a2;
    int a3 = (k3 < 0) ? 4 : ((k3 > 3) ? -4 : 0); k3 += a3; r3f += (float)a3;

    float dl0 = (e0 - r0f) * 0.25f;
    float dl1 = (e1 - r1f) * 0.25f;
    float dl2 = (e2 - r2f) * 0.25f;
    float dl3 = (e3 - r3f) * 0.25f;

    float q0 = (k0 == 3) ? dl0 : ((k1 == 3) ? dl1 : ((k2 == 3) ? dl2 : dl3));
    float q1 = (k0 == 2) ? dl0 : ((k1 == 2) ? dl1 : ((k2 == 2) ? dl2 : dl3));
    float q2 = (k0 == 1) ? dl0 : ((k1 == 1) ? dl1 : ((k2 == 1) ? dl2 : dl3));
    float q3 = (k0 == 0) ? dl0 : ((k1 == 0) ? dl1 : ((k2 == 0) ? dl2 : dl3));
    wgt[0] = (q0 + (1.0f - q3)) * win;
    wgt[1] = (q1 - q0) * win;
    wgt[2] = (q2 - q1) * win;
    wgt[3] = (q3 - q2) * win;

    int i0 = (int)r0f, i1 = (int)r1f, i2 = (int)r2f;
    const unsigned P1 = 2654435761u, P2 = 805459861u;
    hh[0] = ((unsigned)i0 ^ ((unsigned)i1 * P1) ^ ((unsigned)i2 * P2)) & (CAPM - 1);
    int b0 = i0 + 1 - ((k0 > 2) ? 4 : 0);
    int b1v = i1 + 1 - ((k1 > 2) ? 4 : 0);
    int b2v = i2 + 1 - ((k2 > 2) ? 4 : 0);
    hh[1] = ((unsigned)b0 ^ ((unsigned)b1v * P1) ^ ((unsigned)b2v * P2)) & (CAPM - 1);
    int c0i = i0 + 2 - ((k0 > 1) ? 4 : 0);
    int c1i = i1 + 2 - ((k1 > 1) ? 4 : 0);
    int c2i = i2 + 2 - ((k2 > 1) ? 4 : 0);
    hh[2] = ((unsigned)c0i ^ ((unsigned)c1i * P1) ^ ((unsigned)c2i * P2)) & (CAPM - 1);
    int e0i = i0 + 3 - ((k0 > 0) ? 4 : 0);
    int e1i = i1 + 3 - ((k1 > 0) ? 4 : 0);
    int e2i = i2 + 3 - ((k2 > 0) ? 4 : 0);
    hh[3] = ((unsigned)e0i ^ ((unsigned)e1i * P1) ^ ((unsigned)e2i * P2)) & (CAPM - 1);
}

// Phase 1: level-major encode (XCD-affine level mapping, verified R4-R7 win).
// feat[level][pid] = packed bf16 (f0,f1); zeros for inactive levels.
// Table gathers are non-temporal (bypass L1 line-fill on random 8 B reads).
__global__ __launch_bounds__(256)
void encode_levels(const float* __restrict__ points,
                   const float* __restrict__ tables,
                   const float* __restrict__ shifts,
                   const float* __restrict__ cons,
                   unsigned* __restrict__ feat,   // [24][N]
                   int N, int nb)
{
    int gb = blockIdx.x;
    int seg = gb / (8 * nb);
    int within = gb - seg * 8 * nb;
    int level = seg * 8 + (within & 7);
    int pid = (within >> 3) * 256 + (int)threadIdx.x;
    if (pid >= N) return;
    float win = cons[NLEV + level];
    unsigned packed = 0u;
    if (win != 0.0f) {
        float px = points[3 * pid + 0];
        float py = points[3 * pid + 1];
        float pz = points[3 * pid + 2];
        float wgt[4]; unsigned hh[4];
        level_setup(px, py, pz, shifts, cons, level, wgt, hh);
        const f32x2* tab = (const f32x2*)tables + (size_t)level * CAPM;
        f32x2 g0 = __builtin_nontemporal_load(tab + hh[0]);
        f32x2 g1 = __builtin_nontemporal_load(tab + hh[1]);
        f32x2 g2 = __builtin_nontemporal_load(tab + hh[2]);
        f32x2 g3 = __builtin_nontemporal_load(tab + hh[3]);
        float f0 = wgt[0] * g0.x + wgt[1] * g1.x + wgt[2] * g2.x + wgt[3] * g3.x;
        float f1 = wgt[0] * g0.y + wgt[1] * g1.y + wgt[2] * g2.y + wgt[3] * g3.y;
        packed = (unsigned)f2bf(f0) | ((unsigned)f2bf(f1) << 16);
    }
    feat[(size_t)level * N + pid] = packed;
}

// Load a bf16 B-operand fragment from a row-major fp32 [K x ld] matrix.
__device__ __forceinline__ bf16x8 load_bfragW(const float* __restrict__ W, int ld,
                                              int kbase, int kmax, int n, int nmax) {
    bf16x8 f;
    #pragma unroll
    for (int j = 0; j < 8; j++) {
        int k = kbase + j;
        float v = (k < kmax && n < nmax) ? W[k * ld + n] : 0.0f;
        f[j] = (short)f2bf(v);
    }
    return f;
}

#define MFMA(a, b, c) __builtin_amdgcn_mfma_f32_16x16x32_bf16((a), (b), (c), 0, 0, 0)

// Phase 2: MFMA MLP, barrier-free (per-wave LDS + lgkmcnt waits only).
// TPW=2 -> 8192 waves (32/CU grid cap) for chain overlap; full-line epilogue.
__global__ __launch_bounds__(256, 4)
void mlp_mfma(const float* __restrict__ points,
              const unsigned* __restrict__ feat,   // [24][N]
              const float* __restrict__ w1, const float* __restrict__ b1,
              const float* __restrict__ w2, const float* __restrict__ b2,
              const float* __restrict__ w3, const float* __restrict__ b3,
              const float* __restrict__ w4, const float* __restrict__ b4,
              float* __restrict__ out, int N)
{
    __shared__ float smem[4][16 * 52];
    int wave = threadIdx.x >> 6;
    int lane = threadIdx.x & 63;
    int ln = lane & 15;
    int quad = lane >> 4;
    int kq = quad * 8;
    float* L = smem[wave];

    // Weight fragments (B-layout: lane holds B[k=quad*8+j][n])
    bf16x8 B1_00 = load_bfragW(w1, 32,      kq, 51,      ln, 32);
    bf16x8 B1_10 = load_bfragW(w1, 32, 32 + kq, 51,      ln, 32);
    bf16x8 B1_01 = load_bfragW(w1, 32,      kq, 51, 16 + ln, 32);
    bf16x8 B1_11 = load_bfragW(w1, 32, 32 + kq, 51, 16 + ln, 32);
    bf16x8 B2_0  = load_bfragW(w2, 32, kq, 32,      ln, 32);
    bf16x8 B2_1  = load_bfragW(w2, 32, kq, 32, 16 + ln, 32);
    bf16x8 B3_0  = load_bfragW(w3, 32, kq, 32,      ln, 32);
    bf16x8 B3_1  = load_bfragW(w3, 32, kq, 32, 16 + ln, 32);
    bf16x8 B4_0  = load_bfragW(w4, 33, kq, 32,      ln, 33);
    bf16x8 B4_1  = load_bfragW(w4, 33, kq, 32, 16 + ln, 33);
    bf16x8 B4_2  = load_bfragW(w4, 33, kq, 32, 32 + ln, 33);
    float b1lo = b1[ln], b1hi = b1[16 + ln];
    float b2lo = b2[ln], b2hi = b2[16 + ln];
    float b3lo = b3[ln], b3hi = b3[16 + ln];
    float b4a = b4[ln], b4b = b4[16 + ln];
    float b4c = (32 + ln < 33) ? b4[32 + ln] : 0.0f;

    int gw = blockIdx.x * 4 + wave;
    for (int t = 0; t < TPW; t++) {
        int tb = (gw * TPW + t) * 16;
        if (tb >= N) break;
        int pm = tb + ln; if (pm >= N) pm = N - 1;

        // A1 low K-tile (k=0..31): levels quad*4 .. quad*4+3, coalesced dwords
        bf16x8 a1lo;
        #pragma unroll
        for (int i = 0; i < 4; i++) {
            unsigned u = feat[(size_t)(quad * 4 + i) * N + pm];
            a1lo[2 * i]     = (short)(u & 0xFFFFu);
            a1lo[2 * i + 1] = (short)(u >> 16);
        }
        // A1 high K-tile (k=32..63): quad0/1 -> levels 16..23; quad2 -> coords
        bf16x8 a1hi = {0, 0, 0, 0, 0, 0, 0, 0};
        if (quad < 2) {
            #pragma unroll
            for (int i = 0; i < 4; i++) {
                unsigned u = feat[(size_t)(16 + quad * 4 + i) * N + pm];
                a1hi[2 * i]     = (short)(u & 0xFFFFu);
                a1hi[2 * i + 1] = (short)(u >> 16);
            }
        } else if (quad == 2) {
            a1hi[0] = (short)f2bf(points[3 * pm + 0] * 0.001f);
            a1hi[1] = (short)f2bf(points[3 * pm + 1] * 0.001f);
            a1hi[2] = (short)f2bf(points[3 * pm + 2] * 0.001f);
        }

        f32x4 c0 = {b1lo, b1lo, b1lo, b1lo};
        f32x4 c1 = {b1hi, b1hi, b1hi, b1hi};
        c0 = MFMA(a1lo, B1_00, c0);
        c0 = MFMA(a1hi, B1_10, c0);
        c1 = MFMA(a1lo, B1_01, c1);
        c1 = MFMA(a1hi, B1_11, c1);

        // gelu -> LDS transpose (C-layout -> A-layout), intra-wave only
        #pragma unroll
        for (int r = 0; r < 4; r++) {
            L[(quad * 4 + r) * 36 + ln]      = gelu_exact(c0[r]);
            L[(quad * 4 + r) * 36 + 16 + ln] = gelu_exact(c1[r]);
        }
        LDS_SYNC();
        f32x4 lo = *(const f32x4*)(L + ln * 36 + kq);
        f32x4 hi = *(const f32x4*)(L + ln * 36 + kq + 4);
        bf16x8 a2;
        a2[0] = (short)f2bf(lo[0]); a2[1] = (short)f2bf(lo[1]);
        a2[2] = (short)f2bf(lo[2]); a2[3] = (short)f2bf(lo[3]);
        a2[4] = (short)f2bf(hi[0]); a2[5] = (short)f2bf(hi[1]);
        a2[6] = (short)f2bf(hi[2]); a2[7] = (short)f2bf(hi[3]);
        LDS_SYNC();   // reads done before next-stage overwrite

        c0 = (f32x4){b2lo, b2lo, b2lo, b2lo};
        c1 = (f32x4){b2hi, b2hi, b2hi, b2hi};
        c0 = MFMA(a2, B2_0, c0);
        c1 = MFMA(a2, B2_1, c1);

        #pragma unroll
        for (int r = 0; r < 4; r++) {
            L[(quad * 4 + r) * 36 + ln]      = gelu_exact(c0[r]);
            L[(quad * 4 + r) * 36 + 16 + ln] = gelu_exact(c1[r]);
        }
        LDS_SYNC();
        lo = *(const f32x4*)(L + ln * 36 + kq);
        hi = *(const f32x4*)(L + ln * 36 + kq + 4);
        bf16x8 a3;
        a3[0] = (short)f2bf(lo[0]); a3[1] = (short)f2bf(lo[1]);
        a3[2] = (short)f2bf(lo[2]); a3[3] = (short)f2bf(lo[3]);
        a3[4] = (short)f2bf(hi[0]); a3[5] = (short)f2bf(hi[1]);
        a3[6] = (short)f2bf(hi[2]); a3[7] = (short)f2bf(hi[3]);
        LDS_SYNC();

        c0 = (f32x4){b3lo, b3lo, b3lo, b3lo};
        c1 = (f32x4){b3hi, b3hi, b3hi, b3hi};
        c0 = MFMA(a3, B3_0, c0);
        c1 = MFMA(a3, B3_1, c1);

        #pragma unroll
        for (int r = 0; r < 4; r++) {
            L[(quad * 4 + r) * 36 + ln]      = gelu_exact(c0[r]);
            L[(quad * 4 + r) * 36 + 16 + ln] = gelu_exact(c1[r]);
        }
        LDS_SYNC();
        lo = *(const f32x4*)(L + ln * 36 + kq);
        hi = *(const f32x4*)(L + ln * 36 + kq + 4);
        bf16x8 a4;
        a4[0] = (short)f2bf(lo[0]); a4[1] = (short)f2bf(lo[1]);
        a4[2] = (short)f2bf(lo[2]); a4[3] = (short)f2bf(lo[3]);
        a4[4] = (short)f2bf(hi[0]); a4[5] = (short)f2bf(hi[1]);
        a4[6] = (short)f2bf(hi[2]); a4[7] = (short)f2bf(hi[3]);
        LDS_SYNC();

        f32x4 d0 = {b4a, b4a, b4a, b4a};
        f32x4 d1 = {b4b, b4b, b4b, b4b};
        f32x4 d2 = {b4c, b4c, b4c, b4c};
        d0 = MFMA(a4, B4_0, d0);
        d1 = MFMA(a4, B4_1, d1);
        d2 = MFMA(a4, B4_2, d2);

        // Epilogue: stage 16x33 (stride 52), then FULL-LINE global writes:
        // geo = 8 instr x 256 B contiguous, sdf = one 64 B store.
        #pragma unroll
        for (int r = 0; r < 4; r++) {
            L[(quad * 4 + r) * 52 + ln]      = d0[r];
            L[(quad * 4 + r) * 52 + 16 + ln] = d1[r];
            L[(quad * 4 + r) * 52 + 32 + ln] = d2[r];
        }
        LDS_SYNC();
        float* geo = out + N + (size_t)tb * 32;
        #pragma unroll
        for (int i = 0; i < 8; i++) {
            int idx = i * 64 + lane;       // 0..511
            int p  = idx >> 5;             // point in tile
            int c2 = idx & 31;             // geom column
            if (tb + p < N)
                geo[idx] = L[p * 52 + 1 + c2];
        }
        if (lane < 16 && tb + lane < N)
            out[tb + lane] = L[lane * 52];
        LDS_SYNC();
    }
}

// Fallback: round-3 verified fused kernel (used only if ws too small).
__global__ __launch_bounds__(256)
void sdf_fused(const float* __restrict__ points,
               const float* __restrict__ tables,
               const float* __restrict__ shifts,
               const float* __restrict__ w1, const float* __restrict__ b1,
               const float* __restrict__ w2, const float* __restrict__ b2,
               const float* __restrict__ w3, const float* __restrict__ b3,
               const float* __restrict__ w4, const float* __restrict__ b4,
               const float* __restrict__ cons,
               float* __restrict__ out, int N)
{
    int pid = blockIdx.x * blockDim.x + threadIdx.x;
    if (pid >= N) return;
    float px = points[3 * pid + 0];
    float py = points[3 * pid + 1];
    float pz = points[3 * pid + 2];
    float h1[32];
    float cx = px * 0.001f, cy = py * 0.001f, cz = pz * 0.001f;
    #pragma unroll
    for (int j = 0; j < 32; j++) {
        float v = b1[j];
        v = fmaf(cx, w1[48 * 32 + j], v);
        v = fmaf(cy, w1[49 * 32 + j], v);
        v = fmaf(cz, w1[50 * 32 + j], v);
        h1[j] = v;
    }
    int La = (int)cons[2 * NLEV];
    #pragma unroll 2
    for (int l = 0; l < La; ++l) {
        float wgt[4]; unsigned hh[4];
        level_setup(px, py, pz, shifts, cons, l, wgt, hh);
        const float2* tab = (const float2*)tables + (size_t)l * CAPM;
        float2 g0 = tab[hh[0]], g1 = tab[hh[1]], g2 = tab[hh[2]], g3 = tab[hh[3]];
        float f0 = wgt[0] * g0.x + wgt[1] * g1.x + wgt[2] * g2.x + wgt[3] * g3.x;
        float f1 = wgt[0] * g0.y + wgt[1] * g1.y + wgt[2] * g2.y + wgt[3] * g3.y;
        const float* wr0 = w1 + (size_t)(2 * l) * 32;
        const float* wr1 = wr0 + 32;
        #pragma unroll
        for (int j = 0; j < 32; j++)
            h1[j] = fmaf(f1, wr1[j], fmaf(f0, wr0[j], h1[j]));
    }
    float g[32];
    #pragma unroll
    for (int i = 0; i < 32; i++) g[i] = gelu_exact(h1[i]);
    float h2[32];
    #pragma unroll
    for (int j = 0; j < 32; j++) h2[j] = b2[j];
    #pragma unroll
    for (int i = 0; i < 32; i++) {
        float gi = g[i];
        #pragma unroll
        for (int j = 0; j < 32; j++) h2[j] = fmaf(gi, w2[i * 32 + j], h2[j]);
    }
    #pragma unroll
    for (int i = 0; i < 32; i++) g[i] = gelu_exact(h2[i]);
    #pragma unroll
    for (int j = 0; j < 32; j++) h1[j] = b3[j];
    #pragma unroll
    for (int i = 0; i < 32; i++) {
        float gi = g[i];
        #pragma unroll
        for (int j = 0; j < 32; j++) h1[j] = fmaf(gi, w3[i * 32 + j], h1[j]);
    }
    #pragma unroll
    for (int i = 0; i < 32; i++) g[i] = gelu_exact(h1[i]);
    float o[33];
    #pragma unroll
    for (int j = 0; j < 33; j++) o[j] = b4[j];
    #pragma unroll
    for (int i = 0; i < 32; i++) {
        float gi = g[i];
        #pragma unroll
        for (int j = 0; j < 33; j++) o[j] = fmaf(gi, w4[i * 33 + j], o[j]);
    }
    out[pid] = o[0];
    float* geo = out + N + (size_t)pid * 32;
    #pragma unroll
    for (int j = 0; j < 32; j += 4) {
        float4 v = make_float4(o[1 + j], o[2 + j], o[3 + j], o[4 + j]);
        *reinterpret_cast<float4*>(geo + j) = v;
    }
}

extern "C" void kernel_launch(void* const* d_in, const int* in_sizes, int n_in,
                              void* d_out, int out_size, void* d_ws, size_t ws_size,
                              hipStream_t stream) {
    const float* points = (const float*)d_in[0];
    const int*   iter_p = (const int*)d_in[1];
    const float* tables = (const float*)d_in[2];
    const float* shifts = (const float*)d_in[3];
    const float* w1 = (const float*)d_in[4];
    const float* b1 = (const float*)d_in[5];
    const float* w2 = (const float*)d_in[6];
    const float* b2 = (const float*)d_in[7];
    const float* w3 = (const float*)d_in[8];
    const float* b3 = (const float*)d_in[9];
    const float* w4 = (const float*)d_in[10];
    const float* b4 = (const float*)d_in[11];
    float* out = (float*)d_out;
    float* ws  = (float*)d_ws;
    int N = in_sizes[0] / 3;

    init_consts<<<1, 64, 0, stream>>>(iter_p, ws);

    size_t needed = 1024 + (size_t)NLEV * (size_t)N * 4;   // consts + feat[24][N]
    int nb = (N + 255) / 256;
    if (ws_size >= needed) {
        unsigned* feat = (unsigned*)((char*)d_ws + 1024);
        encode_levels<<<24 * nb, 256, 0, stream>>>(points, tables, shifts,
                                                   ws, feat, N, nb);
        int ntile = (N + 15) / 16;
        int nwave = (ntile + TPW - 1) / TPW;
        int nblk  = (nwave + 3) / 4;
        mlp_mfma<<<nblk, 256, 0, stream>>>(points, feat,
                                           w1, b1, w2, b2, w3, b3, w4, b4,
                                           out, N);
    } else {
        sdf_fused<<<nb, 256, 0, stream>>>(points, tables, shifts,
                                          w1, b1, w2, b2, w3, b3, w4, b4,
                                          ws, out, N);
    }
}

// Round 10
// 219.389 us; speedup vs baseline: 1.3145x; 1.3145x over previous
//
#include <hip/hip_runtime.h>
#include <math.h>

#define NLEV 24
#define CAPM 262144
#define TPW 4   // tiles (of 16 points) per wave in the MFMA MLP (R7-verified)

typedef __attribute__((ext_vector_type(8))) short bf16x8;
typedef __attribute__((ext_vector_type(4))) float f32x4;
typedef __attribute__((ext_vector_type(2))) float f32x2;

// Intra-wave LDS ordering: DS ops from one wave execute in order; this wait
// makes write results visible to subsequent same-wave reads and stops the
// compiler reordering across it. No block barrier needed (per-wave LDS only).
#define LDS_SYNC() asm volatile("s_waitcnt lgkmcnt(0)" ::: "memory")

__device__ __forceinline__ unsigned short f2bf(float f) {   // RNE fp32->bf16
    unsigned u = __float_as_uint(f);
    u += 0x7FFFu + ((u >> 16) & 1u);
    return (unsigned short)(u >> 16);
}

__device__ __forceinline__ float gelu_exact(float v) {
    return 0.5f * v * (1.0f + erff(v * 0.70710678118654752f));
}

// ws layout: floats [0..23] 1/scale, [24..47] c2f window, [48] La;
// uint feat[24][N] (packed bf16 pair per level/point) from byte 1024.
__global__ void init_consts(const int* __restrict__ iter_p, float* __restrict__ ws) {
    __shared__ float wloc[NLEV];
    int l = threadIdx.x;
    if (l < NLEV) {
        double scale;
        if (l == 0) scale = 1.0;
        else if (l == NLEV - 1) scale = 0.0001;
        else scale = pow(10.0, -((double)(4 * l)) / 23.0);
        float scale_f = (float)scale;                 // reference casts geomspace to fp32
        ws[l] = (float)(1.0 / (double)scale_f);       // correctly-rounded fp32 reciprocal
        float t = (float)iter_p[0] / 10000.0f;
        t = fminf(fmaxf(t, 0.0f), 1.0f);
        float alpha = (0.3f + 0.7f * t) * 24.0f;
        float x = fminf(fmaxf(alpha - (float)l, 0.0f), 1.0f);
        float win = 0.5f * (1.0f - (float)cos(M_PI * (double)x));
        ws[NLEV + l] = win;
        wloc[l] = win;
    }
    __syncthreads();
    if (l == 0) {
        int cnt = 0;
        for (int i = 0; i < NLEV; i++) cnt += (wloc[i] > 0.0f) ? 1 : 0;
        ws[2 * NLEV] = (float)cnt;
    }
}

// Permutohedral lattice setup: verified arithmetic from rounds 1/3/4.
__device__ __forceinline__ void level_setup(
    float px, float py, float pz,
    const float* __restrict__ shifts, const float* __restrict__ cons, int l,
    float* __restrict__ wgt /*4*/, unsigned* __restrict__ hh /*4*/)
{
    const float SF0 = 2.3094010767585034f;  // 4/sqrt(3)
    const float SF1 = 1.3333333333333333f;  // 4/3
    const float SF2 = 0.9428090415820634f;  // 2*sqrt(2)/3

    float win = cons[NLEV + l];
    float inv = cons[l];
    float p0 = fmaf(px, inv, shifts[3 * l + 0]);
    float p1 = fmaf(py, inv, shifts[3 * l + 1]);
    float p2 = fmaf(pz, inv, shifts[3 * l + 2]);
    float c0 = p0 * SF0, c1 = p1 * SF1, c2 = p2 * SF2;
    float s1 = c1 + c2;
    float s0 = c0 + s1;
    float e0 = s0;
    float e1 = s1 - c0;
    float e2 = c2 - 2.0f * c1;
    float e3 = -3.0f * c2;
    float r0f = rintf(e0 * 0.25f) * 4.0f;
    float r1f = rintf(e1 * 0.25f) * 4.0f;
    float r2f = rintf(e2 * 0.25f) * 4.0f;
    float r3f = rintf(e3 * 0.25f) * 4.0f;
    int sum_ = (int)rintf((r0f + r1f + r2f + r3f) * 0.25f);
    float d0 = e0 - r0f, d1 = e1 - r1f, d2 = e2 - r2f, d3 = e3 - r3f;
    int k0 = (int)(d1 > d0) + (int)(d2 > d0) + (int)(d3 > d0) + sum_;
    int k1 = (int)(d0 > d1) + (int)(d2 > d1) + (int)(d3 > d1)
           + (int)(d0 == d1) + sum_;
    int k2 = (int)(d0 > d2) + (int)(d1 > d2) + (int)(d3 > d2)
           + (int)(d0 == d2) + (int)(d1 == d2) + sum_;
    int k3 = (int)(d0 > d3) + (int)(d1 > d3) + (int)(d2 > d3)
           + (int)(d0 == d3) + (int)(d1 == d3) + (int)(d2 == d3) + sum_;
    int a0 = (k0 < 0) ? 4 : ((k0 > 3) ? -4 : 0); k0 += a0; r0f += (float)a0;
    int a1 = (k1 < 0) ? 4 : ((k1 > 3) ? -4 : 0); k1 += a1; r1f += (float)a1;
    int a2 = (k2 < 0) ? 4 : ((k2 > 3) ? -4 : 0); k2 += a2; r2f += (float)a2;
    int a3 = (k3 < 0) ? 4 : ((k3 > 3) ? -4 : 0); k3 += a3; r3f += (float)a3;

    float dl0 = (e0 - r0f) * 0.25f;
    float dl1 = (e1 - r1f) * 0.25f;
    float dl2 = (e2 - r2f) * 0.25f;
    float dl3 = (e3 - r3f) * 0.25f;

    float q0 = (k0 == 3) ? dl0 : ((k1 == 3) ? dl1 : ((k2 == 3) ? dl2 : dl3));
    float q1 = (k0 == 2) ? dl0 : ((k1 == 2) ? dl1 : ((k2 == 2) ? dl2 : dl3));
    float q2 = (k0 == 1) ? dl0 : ((k1 == 1) ? dl1 : ((k2 == 1) ? dl2 : dl3));
    float q3 = (k0 == 0) ? dl0 : ((k1 == 0) ? dl1 : ((k2 == 0) ? dl2 : dl3));
    wgt[0] = (q0 + (1.0f - q3)) * win;
    wgt[1] = (q1 - q0) * win;
    wgt[2] = (q2 - q1) * win;
    wgt[3] = (q3 - q2) * win;

    int i0 = (int)r0f, i1 = (int)r1f, i2 = (int)r2f;
    const unsigned P1 = 2654435761u, P2 = 805459861u;
    hh[0] = ((unsigned)i0 ^ ((unsigned)i1 * P1) ^ ((unsigned)i2 * P2)) & (CAPM - 1);
    int b0 = i0 + 1 - ((k0 > 2) ? 4 : 0);
    int b1v = i1 + 1 - ((k1 > 2) ? 4 : 0);
    int b2v = i2 + 1 - ((k2 > 2) ? 4 : 0);
    hh[1] = ((unsigned)b0 ^ ((unsigned)b1v * P1) ^ ((unsigned)b2v * P2)) & (CAPM - 1);
    int c0i = i0 + 2 - ((k0 > 1) ? 4 : 0);
    int c1i = i1 + 2 - ((k1 > 1) ? 4 : 0);
    int c2i = i2 + 2 - ((k2 > 1) ? 4 : 0);
    hh[2] = ((unsigned)c0i ^ ((unsigned)c1i * P1) ^ ((unsigned)c2i * P2)) & (CAPM - 1);
    int e0i = i0 + 3 - ((k0 > 0) ? 4 : 0);
    int e1i = i1 + 3 - ((k1 > 0) ? 4 : 0);
    int e2i = i2 + 3 - ((k2 > 0) ? 4 : 0);
    hh[3] = ((unsigned)e0i ^ ((unsigned)e1i * P1) ^ ((unsigned)e2i * P2)) & (CAPM - 1);
}

// Phase 1: level-major encode (XCD-affine level mapping; PLAIN cached gathers
// — NT loads regressed 2x in R9 by defeating per-XCD L2 residency).
__global__ __launch_bounds__(256)
void encode_levels(const float* __restrict__ points,
                   const float* __restrict__ tables,
                   const float* __restrict__ shifts,
                   const float* __restrict__ cons,
                   unsigned* __restrict__ feat,   // [24][N]
                   int N, int nb)
{
    int gb = blockIdx.x;
    int seg = gb / (8 * nb);
    int within = gb - seg * 8 * nb;
    int level = seg * 8 + (within & 7);
    int pid = (within >> 3) * 256 + (int)threadIdx.x;
    if (pid >= N) return;
    float win = cons[NLEV + level];
    unsigned packed = 0u;
    if (win != 0.0f) {
        float px = points[3 * pid + 0];
        float py = points[3 * pid + 1];
        float pz = points[3 * pid + 2];
        float wgt[4]; unsigned hh[4];
        level_setup(px, py, pz, shifts, cons, level, wgt, hh);
        const f32x2* tab = (const f32x2*)tables + (size_t)level * CAPM;
        f32x2 g0 = tab[hh[0]];
        f32x2 g1 = tab[hh[1]];
        f32x2 g2 = tab[hh[2]];
        f32x2 g3 = tab[hh[3]];
        float f0 = wgt[0] * g0.x + wgt[1] * g1.x + wgt[2] * g2.x + wgt[3] * g3.x;
        float f1 = wgt[0] * g0.y + wgt[1] * g1.y + wgt[2] * g2.y + wgt[3] * g3.y;
        packed = (unsigned)f2bf(f0) | ((unsigned)f2bf(f1) << 16);
    }
    feat[(size_t)level * N + pid] = packed;
}

// Load a bf16 B-operand fragment from a row-major fp32 [K x ld] matrix.
__device__ __forceinline__ bf16x8 load_bfragW(const float* __restrict__ W, int ld,
                                              int kbase, int kmax, int n, int nmax) {
    bf16x8 f;
    #pragma unroll
    for (int j = 0; j < 8; j++) {
        int k = kbase + j;
        float v = (k < kmax && n < nmax) ? W[k * ld + n] : 0.0f;
        f[j] = (short)f2bf(v);
    }
    return f;
}

#define MFMA(a, b, c) __builtin_amdgcn_mfma_f32_16x16x32_bf16((a), (b), (c), 0, 0, 0)

// Phase 2: MFMA MLP, barrier-free (per-wave LDS + lgkmcnt waits only).
// TPW=4 (R7-verified); full-line epilogue (lane-aligned 256 B geo stores).
__global__ __launch_bounds__(256, 4)
void mlp_mfma(const float* __restrict__ points,
              const unsigned* __restrict__ feat,   // [24][N]
              const float* __restrict__ w1, const float* __restrict__ b1,
              const float* __restrict__ w2, const float* __restrict__ b2,
              const float* __restrict__ w3, const float* __restrict__ b3,
              const float* __restrict__ w4, const float* __restrict__ b4,
              float* __restrict__ out, int N)
{
    __shared__ float smem[4][16 * 52];
    int wave = threadIdx.x >> 6;
    int lane = threadIdx.x & 63;
    int ln = lane & 15;
    int quad = lane >> 4;
    int kq = quad * 8;
    float* L = smem[wave];

    // Weight fragments (B-layout: lane holds B[k=quad*8+j][n])
    bf16x8 B1_00 = load_bfragW(w1, 32,      kq, 51,      ln, 32);
    bf16x8 B1_10 = load_bfragW(w1, 32, 32 + kq, 51,      ln, 32);
    bf16x8 B1_01 = load_bfragW(w1, 32,      kq, 51, 16 + ln, 32);
    bf16x8 B1_11 = load_bfragW(w1, 32, 32 + kq, 51, 16 + ln, 32);
    bf16x8 B2_0  = load_bfragW(w2, 32, kq, 32,      ln, 32);
    bf16x8 B2_1  = load_bfragW(w2, 32, kq, 32, 16 + ln, 32);
    bf16x8 B3_0  = load_bfragW(w3, 32, kq, 32,      ln, 32);
    bf16x8 B3_1  = load_bfragW(w3, 32, kq, 32, 16 + ln, 32);
    bf16x8 B4_0  = load_bfragW(w4, 33, kq, 32,      ln, 33);
    bf16x8 B4_1  = load_bfragW(w4, 33, kq, 32, 16 + ln, 33);
    bf16x8 B4_2  = load_bfragW(w4, 33, kq, 32, 32 + ln, 33);
    float b1lo = b1[ln], b1hi = b1[16 + ln];
    float b2lo = b2[ln], b2hi = b2[16 + ln];
    float b3lo = b3[ln], b3hi = b3[16 + ln];
    float b4a = b4[ln], b4b = b4[16 + ln];
    float b4c = (32 + ln < 33) ? b4[32 + ln] : 0.0f;

    int gw = blockIdx.x * 4 + wave;
    for (int t = 0; t < TPW; t++) {
        int tb = (gw * TPW + t) * 16;
        if (tb >= N) break;
        int pm = tb + ln; if (pm >= N) pm = N - 1;

        // A1 low K-tile (k=0..31): levels quad*4 .. quad*4+3, coalesced dwords
        bf16x8 a1lo;
        #pragma unroll
        for (int i = 0; i < 4; i++) {
            unsigned u = feat[(size_t)(quad * 4 + i) * N + pm];
            a1lo[2 * i]     = (short)(u & 0xFFFFu);
            a1lo[2 * i + 1] = (short)(u >> 16);
        }
        // A1 high K-tile (k=32..63): quad0/1 -> levels 16..23; quad2 -> coords
        bf16x8 a1hi = {0, 0, 0, 0, 0, 0, 0, 0};
        if (quad < 2) {
            #pragma unroll
            for (int i = 0; i < 4; i++) {
                unsigned u = feat[(size_t)(16 + quad * 4 + i) * N + pm];
                a1hi[2 * i]     = (short)(u & 0xFFFFu);
                a1hi[2 * i + 1] = (short)(u >> 16);
            }
        } else if (quad == 2) {
            a1hi[0] = (short)f2bf(points[3 * pm + 0] * 0.001f);
            a1hi[1] = (short)f2bf(points[3 * pm + 1] * 0.001f);
            a1hi[2] = (short)f2bf(points[3 * pm + 2] * 0.001f);
        }

        f32x4 c0 = {b1lo, b1lo, b1lo, b1lo};
        f32x4 c1 = {b1hi, b1hi, b1hi, b1hi};
        c0 = MFMA(a1lo, B1_00, c0);
        c0 = MFMA(a1hi, B1_10, c0);
        c1 = MFMA(a1lo, B1_01, c1);
        c1 = MFMA(a1hi, B1_11, c1);

        // gelu -> LDS transpose (C-layout -> A-layout), intra-wave only
        #pragma unroll
        for (int r = 0; r < 4; r++) {
            L[(quad * 4 + r) * 36 + ln]      = gelu_exact(c0[r]);
            L[(quad * 4 + r) * 36 + 16 + ln] = gelu_exact(c1[r]);
        }
        LDS_SYNC();
        f32x4 lo = *(const f32x4*)(L + ln * 36 + kq);
        f32x4 hi = *(const f32x4*)(L + ln * 36 + kq + 4);
        bf16x8 a2;
        a2[0] = (short)f2bf(lo[0]); a2[1] = (short)f2bf(lo[1]);
        a2[2] = (short)f2bf(lo[2]); a2[3] = (short)f2bf(lo[3]);
        a2[4] = (short)f2bf(hi[0]); a2[5] = (short)f2bf(hi[1]);
        a2[6] = (short)f2bf(hi[2]); a2[7] = (short)f2bf(hi[3]);
        LDS_SYNC();   // reads done before next-stage overwrite

        c0 = (f32x4){b2lo, b2lo, b2lo, b2lo};
        c1 = (f32x4){b2hi, b2hi, b2hi, b2hi};
        c0 = MFMA(a2, B2_0, c0);
        c1 = MFMA(a2, B2_1, c1);

        #pragma unroll
        for (int r = 0; r < 4; r++) {
            L[(quad * 4 + r) * 36 + ln]      = gelu_exact(c0[r]);
            L[(quad * 4 + r) * 36 + 16 + ln] = gelu_exact(c1[r]);
        }
        LDS_SYNC();
        lo = *(const f32x4*)(L + ln * 36 + kq);
        hi = *(const f32x4*)(L + ln * 36 + kq + 4);
        bf16x8 a3;
        a3[0] = (short)f2bf(lo[0]); a3[1] = (short)f2bf(lo[1]);
        a3[2] = (short)f2bf(lo[2]); a3[3] = (short)f2bf(lo[3]);
        a3[4] = (short)f2bf(hi[0]); a3[5] = (short)f2bf(hi[1]);
        a3[6] = (short)f2bf(hi[2]); a3[7] = (short)f2bf(hi[3]);
        LDS_SYNC();

        c0 = (f32x4){b3lo, b3lo, b3lo, b3lo};
        c1 = (f32x4){b3hi, b3hi, b3hi, b3hi};
        c0 = MFMA(a3, B3_0, c0);
        c1 = MFMA(a3, B3_1, c1);

        #pragma unroll
        for (int r = 0; r < 4; r++) {
            L[(quad * 4 + r) * 36 + ln]      = gelu_exact(c0[r]);
            L[(quad * 4 + r) * 36 + 16 + ln] = gelu_exact(c1[r]);
        }
        LDS_SYNC();
        lo = *(const f32x4*)(L + ln * 36 + kq);
        hi = *(const f32x4*)(L + ln * 36 + kq + 4);
        bf16x8 a4;
        a4[0] = (short)f2bf(lo[0]); a4[1] = (short)f2bf(lo[1]);
        a4[2] = (short)f2bf(lo[2]); a4[3] = (short)f2bf(lo[3]);
        a4[4] = (short)f2bf(hi[0]); a4[5] = (short)f2bf(hi[1]);
        a4[6] = (short)f2bf(hi[2]); a4[7] = (short)f2bf(hi[3]);
        LDS_SYNC();

        f32x4 d0 = {b4a, b4a, b4a, b4a};
        f32x4 d1 = {b4b, b4b, b4b, b4b};
        f32x4 d2 = {b4c, b4c, b4c, b4c};
        d0 = MFMA(a4, B4_0, d0);
        d1 = MFMA(a4, B4_1, d1);
        d2 = MFMA(a4, B4_2, d2);

        // Epilogue: stage 16x33 (stride 52), then FULL-LINE global writes:
        // geo = 8 instr x 256 B contiguous lane-aligned, sdf = one 64 B store.
        #pragma unroll
        for (int r = 0; r < 4; r++) {
            L[(quad * 4 + r) * 52 + ln]      = d0[r];
            L[(quad * 4 + r) * 52 + 16 + ln] = d1[r];
            L[(quad * 4 + r) * 52 + 32 + ln] = d2[r];
        }
        LDS_SYNC();
        float* geo = out + N + (size_t)tb * 32;
        #pragma unroll
        for (int i = 0; i < 8; i++) {
            int idx = i * 64 + lane;       // 0..511
            int p  = idx >> 5;             // point in tile
            int c2 = idx & 31;             // geom column
            if (tb + p < N)
                geo[idx] = L[p * 52 + 1 + c2];
        }
        if (lane < 16 && tb + lane < N)
            out[tb + lane] = L[lane * 52];
        LDS_SYNC();
    }
}

// Fallback: round-3 verified fused kernel (used only if ws too small).
__global__ __launch_bounds__(256)
void sdf_fused(const float* __restrict__ points,
               const float* __restrict__ tables,
               const float* __restrict__ shifts,
               const float* __restrict__ w1, const float* __restrict__ b1,
               const float* __restrict__ w2, const float* __restrict__ b2,
               const float* __restrict__ w3, const float* __restrict__ b3,
               const float* __restrict__ w4, const float* __restrict__ b4,
               const float* __restrict__ cons,
               float* __restrict__ out, int N)
{
    int pid = blockIdx.x * blockDim.x + threadIdx.x;
    if (pid >= N) return;
    float px = points[3 * pid + 0];
    float py = points[3 * pid + 1];
    float pz = points[3 * pid + 2];
    float h1[32];
    float cx = px * 0.001f, cy = py * 0.001f, cz = pz * 0.001f;
    #pragma unroll
    for (int j = 0; j < 32; j++) {
        float v = b1[j];
        v = fmaf(cx, w1[48 * 32 + j], v);
        v = fmaf(cy, w1[49 * 32 + j], v);
        v = fmaf(cz, w1[50 * 32 + j], v);
        h1[j] = v;
    }
    int La = (int)cons[2 * NLEV];
    #pragma unroll 2
    for (int l = 0; l < La; ++l) {
        float wgt[4]; unsigned hh[4];
        level_setup(px, py, pz, shifts, cons, l, wgt, hh);
        const float2* tab = (const float2*)tables + (size_t)l * CAPM;
        float2 g0 = tab[hh[0]], g1 = tab[hh[1]], g2 = tab[hh[2]], g3 = tab[hh[3]];
        float f0 = wgt[0] * g0.x + wgt[1] * g1.x + wgt[2] * g2.x + wgt[3] * g3.x;
        float f1 = wgt[0] * g0.y + wgt[1] * g1.y + wgt[2] * g2.y + wgt[3] * g3.y;
        const float* wr0 = w1 + (size_t)(2 * l) * 32;
        const float* wr1 = wr0 + 32;
        #pragma unroll
        for (int j = 0; j < 32; j++)
            h1[j] = fmaf(f1, wr1[j], fmaf(f0, wr0[j], h1[j]));
    }
    float g[32];
    #pragma unroll
    for (int i = 0; i < 32; i++) g[i] = gelu_exact(h1[i]);
    float h2[32];
    #pragma unroll
    for (int j = 0; j < 32; j++) h2[j] = b2[j];
    #pragma unroll
    for (int i = 0; i < 32; i++) {
        float gi = g[i];
        #pragma unroll
        for (int j = 0; j < 32; j++) h2[j] = fmaf(gi, w2[i * 32 + j], h2[j]);
    }
    #pragma unroll
    for (int i = 0; i < 32; i++) g[i] = gelu_exact(h2[i]);
    #pragma unroll
    for (int j = 0; j < 32; j++) h1[j] = b3[j];
    #pragma unroll
    for (int i = 0; i < 32; i++) {
        float gi = g[i];
        #pragma unroll
        for (int j = 0; j < 32; j++) h1[j] = fmaf(gi, w3[i * 32 + j], h1[j]);
    }
    #pragma unroll
    for (int i = 0; i < 32; i++) g[i] = gelu_exact(h1[i]);
    float o[33];
    #pragma unroll
    for (int j = 0; j < 33; j++) o[j] = b4[j];
    #pragma unroll
    for (int i = 0; i < 32; i++) {
        float gi = g[i];
        #pragma unroll
        for (int j = 0; j < 33; j++) o[j] = fmaf(gi, w4[i * 33 + j], o[j]);
    }
    out[pid] = o[0];
    float* geo = out + N + (size_t)pid * 32;
    #pragma unroll
    for (int j = 0; j < 32; j += 4) {
        float4 v = make_float4(o[1 + j], o[2 + j], o[3 + j], o[4 + j]);
        *reinterpret_cast<float4*>(geo + j) = v;
    }
}

extern "C" void kernel_launch(void* const* d_in, const int* in_sizes, int n_in,
                              void* d_out, int out_size, void* d_ws, size_t ws_size,
                              hipStream_t stream) {
    const float* points = (const float*)d_in[0];
    const int*   iter_p = (const int*)d_in[1];
    const float* tables = (const float*)d_in[2];
    const float* shifts = (const float*)d_in[3];
    const float* w1 = (const float*)d_in[4];
    const float* b1 = (const float*)d_in[5];
    const float* w2 = (const float*)d_in[6];
    const float* b2 = (const float*)d_in[7];
    const float* w3 = (const float*)d_in[8];
    const float* b3 = (const float*)d_in[9];
    const float* w4 = (const float*)d_in[10];
    const float* b4 = (const float*)d_in[11];
    float* out = (float*)d_out;
    float* ws  = (float*)d_ws;
    int N = in_sizes[0] / 3;

    init_consts<<<1, 64, 0, stream>>>(iter_p, ws);

    size_t needed = 1024 + (size_t)NLEV * (size_t)N * 4;   // consts + feat[24][N]
    int nb = (N + 255) / 256;
    if (ws_size >= needed) {
        unsigned* feat = (unsigned*)((char*)d_ws + 1024);
        encode_levels<<<24 * nb, 256, 0, stream>>>(points, tables, shifts,
                                                   ws, feat, N, nb);
        int ntile = (N + 15) / 16;
        int nwave = (ntile + TPW - 1) / TPW;
        int nblk  = (nwave + 3) / 4;
        mlp_mfma<<<nblk, 256, 0, stream>>>(points, feat,
                                           w1, b1, w2, b2, w3, b3, w4, b4,
                                           out, N);
    } else {
        sdf_fused<<<nb, 256, 0, stream>>>(points, tables, shifts,
                                          w1, b1, w2, b2, w3, b3, w4, b4,
                                          ws, out, N);
    }
}